// Round 2
// baseline (250.533 us; speedup 1.0000x reference)
//
#include <hip/hip_runtime.h>
#include <hip/hip_bf16.h>

// Problem constants
#define NB 4
#define NC 256
#define NN 4096   // H*W
// DQK = 32

typedef __bf16 bf16x8 __attribute__((ext_vector_type(8)));
typedef float f32x4 __attribute__((ext_vector_type(4)));
typedef unsigned short u16x4 __attribute__((ext_vector_type(4)));
typedef unsigned short u16x8 __attribute__((ext_vector_type(8)));
typedef unsigned int u32x4 __attribute__((ext_vector_type(4)));

__device__ __forceinline__ unsigned short f2bf(float f) {
  union { float f; unsigned u; } v; v.f = f;
  unsigned r = v.u + 0x7fffu + ((v.u >> 16) & 1u);   // round-to-nearest-even
  return (unsigned short)(r >> 16);
}
__device__ __forceinline__ float bf2f(unsigned short h) {
  union { unsigned u; float f; } v; v.u = ((unsigned)h) << 16;
  return v.f;
}

// ---------------------------------------------------------------------------
// K0: weights -> bf16 (Wcat = [Wq;Wk] 64x256, Wvb 256x256), zero stats buffer
__global__ __launch_bounds__(256) void k0_prep(const float* __restrict__ Wq,
                                               const float* __restrict__ Wk,
                                               const float* __restrict__ Wv,
                                               unsigned short* __restrict__ Wcat,
                                               unsigned short* __restrict__ Wvb,
                                               float* __restrict__ stats) {
  int tid = blockIdx.x * 256 + threadIdx.x;
  int nt = gridDim.x * 256;
  for (int i = tid; i < 64 * NC; i += nt) {
    int d = i >> 8, c = i & 255;
    float v = (d < 32) ? Wq[d * NC + c] : Wk[(d - 32) * NC + c];
    Wcat[i] = f2bf(v);
  }
  for (int i = tid; i < NC * NC; i += nt) Wvb[i] = f2bf(Wv[i]);
  for (int i = tid; i < 1024; i += nt) stats[i] = 0.f;
}

// ---------------------------------------------------------------------------
// K1: xbf[b][c][n] = bf16(x); xT[b][n][c] = bf16(x) transposed (LDS 64x64 tile)
__global__ __launch_bounds__(256) void k1_cvt_tr(const float* __restrict__ x,
                                                 unsigned short* __restrict__ xbf,
                                                 unsigned short* __restrict__ xT) {
  __shared__ __align__(16) unsigned short lt[64][68];
  int bid = blockIdx.x;            // b*256 + cb*64 + nb
  int b  = bid >> 8;
  int cb = (bid >> 6) & 3;
  int nb = bid & 63;
  int c0 = cb * 64, n0 = nb * 64;
  int t = threadIdx.x;
  int tc = t >> 4;                 // 0..15
  int tn = (t & 15) * 4;           // 0..60
#pragma unroll
  for (int it = 0; it < 4; ++it) {
    int c = c0 + tc + it * 16;
    f32x4 xv = *reinterpret_cast<const f32x4*>(&x[((size_t)b * NC + c) * NN + n0 + tn]);
    u16x4 hv;
    hv[0] = f2bf(xv[0]); hv[1] = f2bf(xv[1]); hv[2] = f2bf(xv[2]); hv[3] = f2bf(xv[3]);
    *reinterpret_cast<u16x4*>(&xbf[((size_t)b * NC + c) * NN + n0 + tn]) = hv;
    *reinterpret_cast<u16x4*>(&lt[tc + it * 16][tn]) = hv;
  }
  __syncthreads();
  int nl = t >> 2;                 // 0..63
  int cl0 = (t & 3) * 16;          // 0..48
  u16x8 o0, o1;
#pragma unroll
  for (int q = 0; q < 8; ++q) o0[q] = lt[cl0 + q][nl];
#pragma unroll
  for (int q = 0; q < 8; ++q) o1[q] = lt[cl0 + 8 + q][nl];
  size_t ro = ((size_t)b * NN + n0 + nl) * NC + c0 + cl0;
  *reinterpret_cast<u16x8*>(&xT[ro]) = o0;
  *reinterpret_cast<u16x8*>(&xT[ro + 8]) = o1;
}

// ---------------------------------------------------------------------------
// K2: Qt[b][i][0..31], Kt[b][i][0..31] (bf16) = (Wq|Wk) . x  (+bias), via MFMA
// A = xT rows (i, k=c contig), B = Wcat rows (d, k=c contig). D: row=i, col=d.
__global__ __launch_bounds__(256, 2) void k2_qk(const unsigned short* __restrict__ xT,
                                                const unsigned short* __restrict__ Wcat,
                                                const float* __restrict__ bq,
                                                const float* __restrict__ bk,
                                                unsigned short* __restrict__ Qt,
                                                unsigned short* __restrict__ Kt) {
  __shared__ __align__(16) unsigned short lt2[64][72];
  int bid = blockIdx.x;            // b*64 + it
  int b = bid >> 6, it = bid & 63;
  int i0 = it * 64;
  int t = threadIdx.x;
  int w = t >> 6, l = t & 63, l15 = l & 15, g = l >> 4;

  f32x4 acc[4];
#pragma unroll
  for (int f = 0; f < 4; ++f) acc[f] = f32x4{0.f, 0.f, 0.f, 0.f};

  const unsigned short* xrow = &xT[((size_t)b * NN + i0 + w * 16 + l15) * NC];
#pragma unroll
  for (int ks = 0; ks < 8; ++ks) {
    bf16x8 a = *reinterpret_cast<const bf16x8*>(&xrow[ks * 32 + g * 8]);
#pragma unroll
    for (int f = 0; f < 4; ++f) {
      bf16x8 bb = *reinterpret_cast<const bf16x8*>(&Wcat[(f * 16 + l15) * NC + ks * 32 + g * 8]);
      acc[f] = __builtin_amdgcn_mfma_f32_16x16x32_bf16(a, bb, acc[f], 0, 0, 0);
    }
  }
#pragma unroll
  for (int f = 0; f < 4; ++f) {
    int d = f * 16 + l15;
    float bias = (f < 2) ? bq[d] : bk[d - 32];
#pragma unroll
    for (int r = 0; r < 4; ++r)
      lt2[w * 16 + g * 4 + r][d] = f2bf(acc[f][r] + bias);
  }
  __syncthreads();
  int il = t >> 2, quad = t & 3;
  u32x4 v0 = *reinterpret_cast<const u32x4*>(&lt2[il][quad * 16]);
  u32x4 v1 = *reinterpret_cast<const u32x4*>(&lt2[il][quad * 16 + 8]);
  unsigned short* dst = (quad < 2) ? &Qt[((size_t)b * NN + i0 + il) * 32 + quad * 16]
                                   : &Kt[((size_t)b * NN + i0 + il) * 32 + (quad - 2) * 16];
  *reinterpret_cast<u32x4*>(dst) = v0;
  *reinterpret_cast<u32x4*>(&dst[8]) = v1;
}

// ---------------------------------------------------------------------------
// K3: invD[b][i] = 1 / sum_j exp(S[i,j]).  Block = 16 i-rows; waves split j.
__global__ __launch_bounds__(256, 4) void k3_rowsum(const unsigned short* __restrict__ Qt,
                                                    const unsigned short* __restrict__ Kt,
                                                    float* __restrict__ invD) {
  __shared__ float sred[4][16];
  int bid = blockIdx.x;            // b*256 + it16
  int b = bid >> 8, it = bid & 255;
  int i0 = it * 16;
  int t = threadIdx.x, w = t >> 6, l = t & 63, l15 = l & 15, g = l >> 4;
  bf16x8 a = *reinterpret_cast<const bf16x8*>(&Qt[((size_t)b * NN + i0 + l15) * 32 + g * 8]);
  float rs0 = 0.f, rs1 = 0.f, rs2 = 0.f, rs3 = 0.f;
  int jbase = w * 1024;
  for (int jc = 0; jc < 16; ++jc) {
    int jb = jbase + jc * 64;
#pragma unroll
    for (int f = 0; f < 4; ++f) {
      bf16x8 bb = *reinterpret_cast<const bf16x8*>(&Kt[((size_t)b * NN + jb + f * 16 + l15) * 32 + g * 8]);
      f32x4 s = __builtin_amdgcn_mfma_f32_16x16x32_bf16(a, bb, f32x4{0.f, 0.f, 0.f, 0.f}, 0, 0, 0);
      rs0 += __expf(s[0]); rs1 += __expf(s[1]); rs2 += __expf(s[2]); rs3 += __expf(s[3]);
    }
  }
#pragma unroll
  for (int m = 1; m < 16; m <<= 1) {
    rs0 += __shfl_xor(rs0, m); rs1 += __shfl_xor(rs1, m);
    rs2 += __shfl_xor(rs2, m); rs3 += __shfl_xor(rs3, m);
  }
  if (l15 == 0) {
    sred[w][g * 4 + 0] = rs0; sred[w][g * 4 + 1] = rs1;
    sred[w][g * 4 + 2] = rs2; sred[w][g * 4 + 3] = rs3;
  }
  __syncthreads();
  if (t < 16) {
    float d = sred[0][t] + sred[1][t] + sred[2][t] + sred[3][t];
    invD[(size_t)b * NN + i0 + t] = 1.0f / d;
  }
}

// ---------------------------------------------------------------------------
// K4: fused  S-tile -> P=exp(S)*invD -> T[c',j] += xbf[c',i]*P[i,j], + colsum s[j]
// Block: (b, ih half of i-range, jt 64-wide j-tile). 4 waves split c' (64 each).
// P staged in XOR-swizzled LDS (write b64, read b128 B-fragments).
__global__ __launch_bounds__(256, 2) void k4_attn(const unsigned short* __restrict__ xbf,
                                                  const unsigned short* __restrict__ Qt,
                                                  const unsigned short* __restrict__ Kt,
                                                  const float* __restrict__ invD,
                                                  unsigned short* __restrict__ TtL,
                                                  unsigned short* __restrict__ TtH,
                                                  float* __restrict__ sLo,
                                                  float* __restrict__ sHi) {
  __shared__ __align__(16) unsigned short plt[4096];  // 64 j-rows x 64 i (swizzled 16B units)
  __shared__ float sArr[4][64];
  int bid = blockIdx.x;            // b*128 + ih*64 + jt
  int b = bid >> 7, ih = (bid >> 6) & 1, jt = bid & 63;
  int j0 = jt * 64;
  int t = threadIdx.x, w = t >> 6, l = t & 63, l15 = l & 15, g = l >> 4;
  unsigned short* Tt = ih ? TtH : TtL;
  float* scol = ih ? sHi : sLo;

  bf16x8 bkf[4];
#pragma unroll
  for (int f = 0; f < 4; ++f)
    bkf[f] = *reinterpret_cast<const bf16x8*>(&Kt[((size_t)b * NN + j0 + f * 16 + l15) * 32 + g * 8]);

  f32x4 acc[4][4];
#pragma unroll
  for (int ci = 0; ci < 4; ++ci)
#pragma unroll
    for (int f = 0; f < 4; ++f) acc[ci][f] = f32x4{0.f, 0.f, 0.f, 0.f};
  float scs[4] = {0.f, 0.f, 0.f, 0.f};

  for (int ic = 0; ic < 32; ++ic) {
    int ibase = (ih * 32 + ic) * 64;
    // ---- S phase: wave w computes rows [16w,16w+16) of the 64x64 S tile
    bf16x8 aq = *reinterpret_cast<const bf16x8*>(&Qt[((size_t)b * NN + ibase + w * 16 + l15) * 32 + g * 8]);
    f32x4 inv4 = *reinterpret_cast<const f32x4*>(&invD[(size_t)b * NN + ibase + w * 16 + g * 4]);
#pragma unroll
    for (int f = 0; f < 4; ++f) {
      f32x4 s = __builtin_amdgcn_mfma_f32_16x16x32_bf16(aq, bkf[f], f32x4{0.f, 0.f, 0.f, 0.f}, 0, 0, 0);
      float p0 = __expf(s[0]) * inv4[0];
      float p1 = __expf(s[1]) * inv4[1];
      float p2 = __expf(s[2]) * inv4[2];
      float p3 = __expf(s[3]) * inv4[3];
      scs[f] += (p0 + p1) + (p2 + p3);
      int j = f * 16 + l15;
      int u = (2 * w + (g >> 1)) ^ (j & 7);          // 16B-unit swizzle
      int idx = j * 64 + u * 8 + (g & 1) * 4;        // ushort units
      u16x4 pk;
      pk[0] = f2bf(p0); pk[1] = f2bf(p1); pk[2] = f2bf(p2); pk[3] = f2bf(p3);
      *reinterpret_cast<u16x4*>(&plt[idx]) = pk;
    }
    __syncthreads();
    // ---- T phase: acc[c',j] += xbf[c', i] * P[i, j]
#pragma unroll
    for (int kb = 0; kb < 2; ++kb) {
      bf16x8 ax[4];
#pragma unroll
      for (int ci = 0; ci < 4; ++ci)
        ax[ci] = *reinterpret_cast<const bf16x8*>(
            &xbf[((size_t)b * NC + w * 64 + ci * 16 + l15) * NN + ibase + kb * 32 + g * 8]);
      bf16x8 bp[4];
#pragma unroll
      for (int f = 0; f < 4; ++f) {
        int j = f * 16 + l15;
        int u = (4 * kb + g) ^ (j & 7);
        bp[f] = *reinterpret_cast<const bf16x8*>(&plt[j * 64 + u * 8]);
      }
#pragma unroll
      for (int ci = 0; ci < 4; ++ci)
#pragma unroll
        for (int f = 0; f < 4; ++f)
          acc[ci][f] = __builtin_amdgcn_mfma_f32_16x16x32_bf16(ax[ci], bp[f], acc[ci][f], 0, 0, 0);
    }
    __syncthreads();
  }
  // ---- colsum epilogue: s[j] = sum_i P[i,j] over this block's i-half
#pragma unroll
  for (int f = 0; f < 4; ++f) {
    scs[f] += __shfl_xor(scs[f], 16);
    scs[f] += __shfl_xor(scs[f], 32);
  }
  if (l < 16) {
#pragma unroll
    for (int f = 0; f < 4; ++f) sArr[w][f * 16 + l] = scs[f];
  }
  __syncthreads();
  if (t < 64) scol[(size_t)b * NN + j0 + t] = sArr[0][t] + sArr[1][t] + sArr[2][t] + sArr[3][t];
  // ---- Tt store: Tt[b][j][c'] bf16
#pragma unroll
  for (int ci = 0; ci < 4; ++ci)
#pragma unroll
    for (int f = 0; f < 4; ++f) {
      u16x4 pk;
      pk[0] = f2bf(acc[ci][f][0]); pk[1] = f2bf(acc[ci][f][1]);
      pk[2] = f2bf(acc[ci][f][2]); pk[3] = f2bf(acc[ci][f][3]);
      *reinterpret_cast<u16x4*>(
          &Tt[((size_t)b * NN + j0 + f * 16 + l15) * NC + w * 64 + ci * 16 + g * 4]) = pk;
    }
}

// ---------------------------------------------------------------------------
// K5: out[c,j] = sum_c' Wv[c,c'] * (T_lo+T_hi)[c',j] + bv[c]*(s_lo+s_hi)[j]
//     + BN partial sums (sum, sumsq per channel) via atomics. out stored bf16.
__global__ __launch_bounds__(256, 2) void k5_out(const unsigned short* __restrict__ Wvb,
                                                 const unsigned short* __restrict__ TtL,
                                                 const unsigned short* __restrict__ TtH,
                                                 const float* __restrict__ sLo,
                                                 const float* __restrict__ sHi,
                                                 const float* __restrict__ bv,
                                                 unsigned short* __restrict__ outbf,
                                                 float* __restrict__ stats) {
  int bid = blockIdx.x;            // b*64 + jt
  int b = bid >> 6, jt = bid & 63;
  int j0 = jt * 64;
  int t = threadIdx.x, w = t >> 6, l = t & 63, l15 = l & 15, g = l >> 4;
  f32x4 acc[4][4];
#pragma unroll
  for (int ci = 0; ci < 4; ++ci)
#pragma unroll
    for (int f = 0; f < 4; ++f) acc[ci][f] = f32x4{0.f, 0.f, 0.f, 0.f};

#pragma unroll
  for (int h = 0; h < 2; ++h) {
    const unsigned short* T = h ? TtH : TtL;
#pragma unroll
    for (int ks = 0; ks < 8; ++ks) {
      bf16x8 a[4], bb[4];
#pragma unroll
      for (int ci = 0; ci < 4; ++ci)
        a[ci] = *reinterpret_cast<const bf16x8*>(&Wvb[(w * 64 + ci * 16 + l15) * NC + ks * 32 + g * 8]);
#pragma unroll
      for (int f = 0; f < 4; ++f)
        bb[f] = *reinterpret_cast<const bf16x8*>(&T[((size_t)b * NN + j0 + f * 16 + l15) * NC + ks * 32 + g * 8]);
#pragma unroll
      for (int ci = 0; ci < 4; ++ci)
#pragma unroll
        for (int f = 0; f < 4; ++f)
          acc[ci][f] = __builtin_amdgcn_mfma_f32_16x16x32_bf16(a[ci], bb[f], acc[ci][f], 0, 0, 0);
    }
  }
  float sv[4];
#pragma unroll
  for (int f = 0; f < 4; ++f) {
    size_t ji = (size_t)b * NN + j0 + f * 16 + l15;
    sv[f] = sLo[ji] + sHi[ji];
  }
#pragma unroll
  for (int ci = 0; ci < 4; ++ci) {
    f32x4 bv4 = *reinterpret_cast<const f32x4*>(&bv[w * 64 + ci * 16 + g * 4]);
#pragma unroll
    for (int r = 0; r < 4; ++r) {
      int c = w * 64 + ci * 16 + g * 4 + r;
      float vsum = 0.f, vsq = 0.f;
#pragma unroll
      for (int f = 0; f < 4; ++f) {
        float v = acc[ci][f][r] + bv4[r] * sv[f];
        outbf[((size_t)b * NC + c) * NN + j0 + f * 16 + l15] = f2bf(v);
        vsum += v; vsq += v * v;
      }
#pragma unroll
      for (int m = 1; m < 16; m <<= 1) { vsum += __shfl_xor(vsum, m); vsq += __shfl_xor(vsq, m); }
      if (l15 == 0) { atomicAdd(&stats[c], vsum); atomicAdd(&stats[256 + c], vsq); }
    }
  }
}

// ---------------------------------------------------------------------------
// K6: finalize BN -> per-channel scale/shift (already x1e-5 folded)
__global__ __launch_bounds__(256) void k6_fin(const float* __restrict__ gamma,
                                              const float* __restrict__ beta,
                                              float* __restrict__ stats) {
  int c = threadIdx.x;
  float mean = stats[c] * (1.0f / 16384.0f);
  float var = stats[256 + c] * (1.0f / 16384.0f) - mean * mean;
  float rstd = rsqrtf(var + 1e-5f);
  float sc = gamma[c] * rstd;
  stats[512 + c] = sc * 1e-5f;
  stats[768 + c] = (beta[c] - mean * sc) * 1e-5f;
}

// ---------------------------------------------------------------------------
// K7: y = x + outbf*scale[c] + shift[c]
__global__ __launch_bounds__(256) void k7_final(const float* __restrict__ x,
                                                const unsigned short* __restrict__ outbf,
                                                const float* __restrict__ stats,
                                                float* __restrict__ y) {
  int tid = blockIdx.x * 256 + threadIdx.x;
  size_t base = (size_t)tid * 8;
  int c = (int)((base >> 12) & 255);
  float sc = stats[512 + c], sh = stats[768 + c];
  u16x8 ov = *reinterpret_cast<const u16x8*>(&outbf[base]);
  f32x4 x0 = *reinterpret_cast<const f32x4*>(&x[base]);
  f32x4 x1 = *reinterpret_cast<const f32x4*>(&x[base + 4]);
  f32x4 y0, y1;
#pragma unroll
  for (int q = 0; q < 4; ++q) y0[q] = x0[q] + bf2f(ov[q]) * sc + sh;
#pragma unroll
  for (int q = 0; q < 4; ++q) y1[q] = x1[q] + bf2f(ov[4 + q]) * sc + sh;
  *reinterpret_cast<f32x4*>(&y[base]) = y0;
  *reinterpret_cast<f32x4*>(&y[base + 4]) = y1;
}

// ---------------------------------------------------------------------------
extern "C" void kernel_launch(void* const* d_in, const int* in_sizes, int n_in,
                              void* d_out, int out_size, void* d_ws, size_t ws_size,
                              hipStream_t stream) {
  (void)in_sizes; (void)n_in; (void)out_size;
  if (ws_size < 27627520) return;  // workspace layout requires ~26.4 MB

  const float* x    = (const float*)d_in[0];
  const float* Wq   = (const float*)d_in[1];
  const float* bq   = (const float*)d_in[2];
  const float* Wk   = (const float*)d_in[3];
  const float* bk   = (const float*)d_in[4];
  const float* Wv   = (const float*)d_in[5];
  const float* bv   = (const float*)d_in[6];
  const float* gam  = (const float*)d_in[7];
  const float* bet  = (const float*)d_in[8];
  float* y = (float*)d_out;
  char* ws = (char*)d_ws;

  unsigned short* xbf  = (unsigned short*)(ws + 0);          // 8 MB; reused as outbf after K4
  unsigned short* xT   = (unsigned short*)(ws + 8388608);    // 8 MB; reused as Tt_lo after K2
  unsigned short* Qt   = (unsigned short*)(ws + 16777216);   // 1 MB
  unsigned short* Kt   = (unsigned short*)(ws + 17825792);   // 1 MB
  float* invD          = (float*)(ws + 18874368);            // 64 KB
  unsigned short* TtH  = (unsigned short*)(ws + 18939904);   // 8 MB
  float* sLo           = (float*)(ws + 27328512);            // 64 KB
  float* sHi           = (float*)(ws + 27394048);            // 64 KB
  float* stats         = (float*)(ws + 27459584);            // 4 KB
  unsigned short* Wcat = (unsigned short*)(ws + 27463680);   // 32 KB
  unsigned short* Wvb  = (unsigned short*)(ws + 27496448);   // 128 KB
  unsigned short* TtL  = xT;
  unsigned short* outbf = xbf;

  hipLaunchKernelGGL(k0_prep,  dim3(256),  dim3(256), 0, stream, Wq, Wk, Wv, Wcat, Wvb, stats);
  hipLaunchKernelGGL(k1_cvt_tr,dim3(1024), dim3(256), 0, stream, x, xbf, xT);
  hipLaunchKernelGGL(k2_qk,    dim3(256),  dim3(256), 0, stream, xT, Wcat, bq, bk, Qt, Kt);
  hipLaunchKernelGGL(k3_rowsum,dim3(1024), dim3(256), 0, stream, Qt, Kt, invD);
  hipLaunchKernelGGL(k4_attn,  dim3(512),  dim3(256), 0, stream, xbf, Qt, Kt, invD, TtL, TtH, sLo, sHi);
  hipLaunchKernelGGL(k5_out,   dim3(256),  dim3(256), 0, stream, Wvb, TtL, TtH, sLo, sHi, bv, outbf, stats);
  hipLaunchKernelGGL(k6_fin,   dim3(1),    dim3(256), 0, stream, gam, bet, stats);
  hipLaunchKernelGGL(k7_final, dim3(2048), dim3(256), 0, stream, x, outbf, stats, y);
}